// Round 20
// baseline (320.720 us; speedup 1.0000x reference)
//
#include <hip/hip_runtime.h>
#include <hip/hip_bf16.h>

#define SEQ 2048
#define BATCH 4
#define DM 1024
#define HEADS 16
#define DK 64
#define NBH 64
#define SC_LOG2E (0.125f * 1.4426950408889634f)

typedef unsigned short u16;
typedef __attribute__((ext_vector_type(8))) short bf16x8;
typedef __attribute__((ext_vector_type(4))) float f32x4;

__device__ inline u16 f2bf(float f) {
    unsigned int u = __builtin_bit_cast(unsigned int, f);
    u += 0x7fffu + ((u >> 16) & 1u);   // RNE
    return (u16)(u >> 16);
}
__device__ inline float fexp2(float x) {
    float r; asm("v_exp_f32 %0, %1" : "=v"(r) : "v"(x)); return r;
}
__device__ inline unsigned pkbf(float a, float b) {   // lo=a, hi=b (RNE)
    unsigned r; asm("v_cvt_pk_bf16_f32 %0, %1, %2" : "=v"(r) : "v"(a), "v"(b)); return r;
}

// ---------------- weights-only fp32 -> bf16 conversion (24 MB ~ 5 us) -------
__global__ __launch_bounds__(256)
void conv_w(const float* __restrict__ wq, const float* __restrict__ wk,
            const float* __restrict__ wv, const float* __restrict__ wo,
            u16* __restrict__ ow)
{
    const size_t W8 = (size_t)DM * DM / 8;             // 131,072
    size_t i = (size_t)blockIdx.x * 256 + threadIdx.x; // grid 2048 = 4*W8/256
    int wsel = (int)(i >> 17);
    size_t off = i & (W8 - 1);
    const float* src = wsel == 0 ? wq : wsel == 1 ? wk : wsel == 2 ? wv : wo;
    u16* dst = ow + (size_t)wsel * DM * DM;
    float4 a = ((const float4*)src)[off * 2];
    float4 b = ((const float4*)src)[off * 2 + 1];
    uint4 w;
    w.x = pkbf(a.x, a.y); w.y = pkbf(a.z, a.w);
    w.z = pkbf(b.x, b.y); w.w = pkbf(b.z, b.w);
    *(uint4*)(dst + off * 8) = w;
}

// ---------------- shared GEMM pieces ------------------
__device__ inline void gstage(const u16* __restrict__ src, u16* dst,
                              int wave, int lane) {
    #pragma unroll
    for (int i = 0; i < 4; ++i) {
        int ci = (i * 4 + wave) * 64 + lane;
        int row = ci >> 3, ch = ci & 7;
        const u16* g = src + (size_t)row * 1024 + ((ch ^ (row & 7)) << 3);
        u16* l = dst + (i * 4 + wave) * 512;
        __builtin_amdgcn_global_load_lds(
            (const __attribute__((address_space(1))) unsigned int*)g,
            (__attribute__((address_space(3))) unsigned int*)l, 16, 0, 0);
    }
}
__device__ inline bf16x8 rdt(const u16* t, int row, int ch) {
    return *(const bf16x8*)(t + row * 64 + ((ch ^ (row & 7)) << 3));
}

// ---------------- bf16-A GEMM (output projection, fp32 out; r16 exact) ------
__global__ __launch_bounds__(256, 2)
void gemm_bf(const u16* __restrict__ A, const u16* __restrict__ B,
             const float* __restrict__ bias, float* __restrict__ Out)
{
    __shared__ __align__(16) u16 sA[2][128 * 64];
    __shared__ __align__(16) u16 sB[2][128 * 64];
    const int tid  = threadIdx.x;
    const int lane = tid & 63, wave = tid >> 6;
    const int wr = (wave >> 1) * 64, wc = (wave & 1) * 64;
    const int l15 = lane & 15, lg = lane >> 4;
    const int row0 = blockIdx.x * 128, col0 = blockIdx.y * 128;
    const u16* Abase = A + (size_t)row0 * 1024;
    const u16* Bbase = B + (size_t)col0 * 1024;

    f32x4 acc[4][4];
    #pragma unroll
    for (int m = 0; m < 4; ++m)
        #pragma unroll
        for (int n = 0; n < 4; ++n) acc[m][n] = (f32x4){0.f, 0.f, 0.f, 0.f};

    gstage(Abase, sA[0], wave, lane);
    gstage(Bbase, sB[0], wave, lane);
    __syncthreads();

    int cur = 0;
    for (int kt = 0; kt < 16; ++kt) {
        if (kt < 15) {
            gstage(Abase + (kt + 1) * 64, sA[cur ^ 1], wave, lane);
            gstage(Bbase + (kt + 1) * 64, sB[cur ^ 1], wave, lane);
        }
        #pragma unroll
        for (int s = 0; s < 2; ++s) {
            bf16x8 af[4], bf[4];
            #pragma unroll
            for (int m = 0; m < 4; ++m)
                af[m] = rdt(sA[cur], wr + m * 16 + l15, s * 4 + lg);
            #pragma unroll
            for (int n = 0; n < 4; ++n)
                bf[n] = rdt(sB[cur], wc + n * 16 + l15, s * 4 + lg);
            __builtin_amdgcn_s_setprio(1);
            #pragma unroll
            for (int m = 0; m < 4; ++m)
                #pragma unroll
                for (int n = 0; n < 4; ++n)
                    acc[m][n] = __builtin_amdgcn_mfma_f32_16x16x32_bf16(
                        af[m], bf[n], acc[m][n], 0, 0, 0);
            __builtin_amdgcn_s_setprio(0);
        }
        __syncthreads();
        cur ^= 1;
    }
    #pragma unroll
    for (int m = 0; m < 4; ++m)
        #pragma unroll
        for (int n = 0; n < 4; ++n)
            #pragma unroll
            for (int r = 0; r < 4; ++r) {
                int R = row0 + wr + m * 16 + lg * 4 + r;
                int E = col0 + wc + n * 16 + l15;
                Out[(size_t)R * 1024 + E] = acc[m][n][r] + bias[E];
            }
}

// ---------------- merged Q/K/V projection GEMM (counted-vmcnt pipeline) -----
// r16 structure (sA single-buffer, 48KB, 3 blocks/CU) + T4: raw s_barrier
// with counted s_waitcnt vmcnt(8) so the 2-deep A-register prefetch
// (loadA(kt+2)) stays in flight ACROSS barriers.  Wait accounting per iter:
// outstanding 20 = loadA(kt+1)[8 oldest] + gstage(kt+1)[4] + loadA(kt+2)[8
// newest]; vmcnt(8) drains exactly the first 12.  Tail peeled (kt=14: vmcnt(0)).
__global__ __launch_bounds__(256, 3)
void gemm_qkv(const float* __restrict__ q, const float* __restrict__ k,
              const float* __restrict__ v, const u16* __restrict__ Wbf,
              const float* __restrict__ bq, const float* __restrict__ bk,
              const float* __restrict__ bv,
              u16* __restrict__ Qb, u16* __restrict__ Kb, u16* __restrict__ Vt)
{
    __shared__ __align__(16) u16 sA[128 * 64];       // single buffer
    __shared__ __align__(16) u16 sB[2][128 * 64];
    const int g = blockIdx.y >> 3;                 // 0=Q, 1=K, 2=V
    const float* A    = g == 0 ? q  : g == 1 ? k  : v;
    const float* bias = g == 0 ? bq : g == 1 ? bk : bv;
    u16* Out          = g == 0 ? Qb : g == 1 ? Kb : Vt;
    const u16* B = Wbf + (size_t)g * DM * DM;
    const float oscale = g == 0 ? SC_LOG2E : 1.0f;
    const bool vmode = (g == 2);

    const int tid  = threadIdx.x;
    const int lane = tid & 63, wave = tid >> 6;
    const int wr = (wave >> 1) * 64, wc = (wave & 1) * 64;
    const int l15 = lane & 15, lg = lane >> 4;
    const int row0 = blockIdx.x * 128, col0 = (blockIdx.y & 7) * 128;
    const int arow = tid >> 4;          // 16 lanes per A row
    const int ach  = tid & 15;          // 16B chunk within the row's 256B slab
    const float* Ag = A + (size_t)(row0 + arow) * 1024 + ach * 4;
    const u16* Bbase = B + (size_t)col0 * 1024;

    f32x4 acc[4][4];
    #pragma unroll
    for (int m = 0; m < 4; ++m)
        #pragma unroll
        for (int n = 0; n < 4; ++n) acc[m][n] = (f32x4){0.f, 0.f, 0.f, 0.f};

    auto loadA = [&](int kt, float4* r) {
        #pragma unroll
        for (int i = 0; i < 8; ++i)     // pass i: rows arow + 16*i
            r[i] = *(const float4*)(Ag + (size_t)i * 16 * 1024 + kt * 64);
    };
    auto writeA = [&](const float4* r) {
        const int c16 = ach >> 1, half = ach & 1;
        #pragma unroll
        for (int i = 0; i < 8; ++i) {
            int row = arow + 16 * i;
            uint2 w;
            w.x = pkbf(r[i].x, r[i].y);
            w.y = pkbf(r[i].z, r[i].w);
            *(uint2*)(sA + row * 64 + ((c16 ^ (row & 7)) << 3) + half * 4) = w;
        }
    };
    auto mfma_step = [&](const u16* sBc) {
        #pragma unroll
        for (int s = 0; s < 2; ++s) {
            bf16x8 af[4], bf[4];
            #pragma unroll
            for (int m = 0; m < 4; ++m)
                af[m] = rdt(sA, wr + m * 16 + l15, s * 4 + lg);
            #pragma unroll
            for (int n = 0; n < 4; ++n)
                bf[n] = rdt(sBc, wc + n * 16 + l15, s * 4 + lg);
            __builtin_amdgcn_s_setprio(1);
            #pragma unroll
            for (int m = 0; m < 4; ++m)
                #pragma unroll
                for (int n = 0; n < 4; ++n)
                    acc[m][n] = __builtin_amdgcn_mfma_f32_16x16x32_bf16(
                        af[m], bf[n], acc[m][n], 0, 0, 0);
            __builtin_amdgcn_s_setprio(0);
        }
    };

    float4 aP[8], aN[8];
    {
        float4 a0[8];
        loadA(0, a0);
        gstage(Bbase, sB[0], wave, lane);
        asm volatile("s_waitcnt vmcnt(0)" ::: "memory");
        __builtin_amdgcn_sched_barrier(0);
        writeA(a0);
        loadA(1, aP);                          // 8 in flight entering the loop
        asm volatile("s_waitcnt lgkmcnt(0)" ::: "memory");
        __builtin_amdgcn_sched_barrier(0);
        __builtin_amdgcn_s_barrier();
    }

    int cur = 0;
    #pragma unroll 2
    for (int kt = 0; kt < 14; ++kt) {
        gstage(Bbase + (kt + 1) * 64, sB[cur ^ 1], wave, lane);   // 4 ops
        loadA(kt + 2, aN);                                        // 8 ops, newest
        mfma_step(sB[cur]);
        asm volatile("s_waitcnt vmcnt(8)" ::: "memory");   // drain loadA(kt+1)+gstage(kt+1)
        __builtin_amdgcn_sched_barrier(0);
        __builtin_amdgcn_s_barrier();            // sA reads done block-wide; sB[cur^1] landed
        writeA(aP);                              // aP = A(kt+1), valid
        #pragma unroll
        for (int j = 0; j < 8; ++j) aP[j] = aN[j];
        asm volatile("s_waitcnt lgkmcnt(0)" ::: "memory");
        __builtin_amdgcn_sched_barrier(0);
        __builtin_amdgcn_s_barrier();            // sA writes visible
        cur ^= 1;
    }
    // kt = 14: last stage + last A write (drain everything)
    gstage(Bbase + 15 * 64, sB[cur ^ 1], wave, lane);
    mfma_step(sB[cur]);
    asm volatile("s_waitcnt vmcnt(0)" ::: "memory");
    __builtin_amdgcn_sched_barrier(0);
    __builtin_amdgcn_s_barrier();
    writeA(aP);                                  // A(15)
    asm volatile("s_waitcnt lgkmcnt(0)" ::: "memory");
    __builtin_amdgcn_sched_barrier(0);
    __builtin_amdgcn_s_barrier();
    cur ^= 1;
    // kt = 15: compute only
    mfma_step(sB[cur]);

    #pragma unroll
    for (int m = 0; m < 4; ++m)
        #pragma unroll
        for (int n = 0; n < 4; ++n)
            #pragma unroll
            for (int r = 0; r < 4; ++r) {
                int R = row0 + wr + m * 16 + lg * 4 + r;
                int E = col0 + wc + n * 16 + l15;
                float val = (acc[m][n][r] + bias[E]) * oscale;
                int s = R >> 2, b = R & 3, hh = E >> 6, d = E & 63;
                size_t idx = vmode
                    ? ((size_t)(b * HEADS + hh) * DK + d) * SEQ + s
                    : ((size_t)(b * HEADS + hh) * SEQ + s) * DK + d;
                Out[idx] = f2bf(val);
            }
}

// ---------------- causal flash attention (round-16 exact) -------------------
__device__ inline void stage_tile(const u16* __restrict__ srcRow0, int srcStride,
                                  u16* tile, int wave, int lane) {
    #pragma unroll
    for (int i = 0; i < 2; ++i) {
        int row = wave * 16 + i * 8 + (lane >> 3);
        int chunk = (lane & 7) ^ (row & 7);
        const u16* g = srcRow0 + (size_t)row * srcStride + chunk * 8;
        u16* l = tile + (wave * 16 + i * 8) * 64;
        __builtin_amdgcn_global_load_lds(
            (const __attribute__((address_space(1))) unsigned int*)g,
            (__attribute__((address_space(3))) unsigned int*)l, 16, 0, 0);
    }
}
__device__ inline bf16x8 tread(const u16* tile, int row, int chunk) {
    return *(const bf16x8*)((const char*)tile + row * 128 + ((chunk ^ (row & 7)) << 4));
}

__global__ __launch_bounds__(256, 4)
void attn_fwd(const u16* __restrict__ Q, const u16* __restrict__ K,
              const u16* __restrict__ V, u16* __restrict__ X)
{
    __shared__ __align__(16) u16 sK[2][4096];
    __shared__ __align__(16) u16 sV[2][4096];
    __shared__ __align__(16) u16 plds[4][16 * 64];

    const int lin = blockIdx.x + 16 * blockIdx.y;
    const int xcd = lin & 7, ii = lin >> 3;
    const int bh  = (ii & 7) | (xcd << 3);   // 8 bh per XCD (KV fits L2)
    const int tA  = ii >> 3;                  // 0..15
    const int tB  = 31 - tA;                  // 16..31
    const int b = bh >> 4, h = bh & 15;
    const int lane = threadIdx.x & 63, wave = threadIdx.x >> 6;
    const int l15 = lane & 15, lg = lane >> 4;
    const int qloc = wave * 16 + l15;
    const int swz = (l15 & 7) << 4;
    const u16* Qh = Q + (size_t)bh * SEQ * DK;
    const u16* Kh = K + (size_t)bh * SEQ * DK;
    const u16* Vh = V + (size_t)bh * SEQ * DK;   // [DK][SEQ]

    const int qA = tA * 64 + wave * 16, qB = tB * 64 + wave * 16;
    const bf16x8 qfA0 = *(const bf16x8*)&Qh[(size_t)(qA + l15) * DK + lg * 8];
    const bf16x8 qfA1 = *(const bf16x8*)&Qh[(size_t)(qA + l15) * DK + 32 + lg * 8];
    const bf16x8 qfB0 = *(const bf16x8*)&Qh[(size_t)(qB + l15) * DK + lg * 8];
    const bf16x8 qfB1 = *(const bf16x8*)&Qh[(size_t)(qB + l15) * DK + 32 + lg * 8];

    f32x4 oA[4], oB[4];
    #pragma unroll
    for (int n = 0; n < 4; ++n) {
        oA[n] = (f32x4){0.f, 0.f, 0.f, 0.f};
        oB[n] = (f32x4){0.f, 0.f, 0.f, 0.f};
    }
    float lsA = 0.f, lsB = 0.f;
    u16* pw = &plds[wave][0];

    auto compute = [&](const u16* kt, const u16* vt,
                       const bf16x8& q0v, const bf16x8& q1v,
                       f32x4* o, float& ls, bool diag) {
        f32x4 sc[4];
        #pragma unroll
        for (int c = 0; c < 4; ++c) sc[c] = (f32x4){0.f, 0.f, 0.f, 0.f};

        __builtin_amdgcn_s_setprio(1);
        #pragma unroll
        for (int c = 0; c < 4; ++c) {
            bf16x8 k0 = tread(kt, 16 * c + l15, lg);
            bf16x8 k1 = tread(kt, 16 * c + l15, 4 + lg);
            sc[c] = __builtin_amdgcn_mfma_f32_16x16x32_bf16(k0, q0v, sc[c], 0, 0, 0);
            sc[c] = __builtin_amdgcn_mfma_f32_16x16x32_bf16(k1, q1v, sc[c], 0, 0, 0);
        }
        __builtin_amdgcn_s_setprio(0);

        #pragma unroll
        for (int c = 0; c < 4; ++c) {
            float p[4];
            #pragma unroll
            for (int r = 0; r < 4; ++r) {
                float e = fexp2(sc[c][r]);
                if (diag) {
                    int kl = 16 * c + 4 * lg + r;
                    e = (kl <= qloc) ? e : 0.f;
                }
                p[r] = e;
                ls += e;
            }
            uint2 w;
            w.x = pkbf(p[0], p[1]);
            w.y = pkbf(p[2], p[3]);
            *(uint2*)((char*)pw + l15 * 128 + ((32 * c + 8 * lg) ^ swz)) = w;
        }
        asm volatile("s_waitcnt lgkmcnt(0)" ::: "memory");
        __builtin_amdgcn_sched_barrier(0);
        bf16x8 pf0 = *(const bf16x8*)((const char*)pw + l15 * 128 + ((16 * lg) ^ swz));
        bf16x8 pf1 = *(const bf16x8*)((const char*)pw + l15 * 128 + ((64 + 16 * lg) ^ swz));

        __builtin_amdgcn_s_setprio(1);
        #pragma unroll
        for (int n = 0; n < 4; ++n) {
            bf16x8 v0 = tread(vt, 16 * n + l15, lg);
            bf16x8 v1 = tread(vt, 16 * n + l15, 4 + lg);
            o[n] = __builtin_amdgcn_mfma_f32_16x16x32_bf16(pf0, v0, o[n], 0, 0, 0);
            o[n] = __builtin_amdgcn_mfma_f32_16x16x32_bf16(pf1, v1, o[n], 0, 0, 0);
        }
        __builtin_amdgcn_s_setprio(0);
    };

    stage_tile(Kh, DK, sK[0], wave, lane);
    stage_tile(Vh, SEQ, sV[0], wave, lane);
    __syncthreads();

    const int nst = tB + 1;
    int cur = 0;
    for (int blk = 0; blk < nst; ++blk) {
        if (blk + 1 < nst) {
            stage_tile(Kh + (size_t)(blk + 1) * 64 * DK, DK, sK[cur ^ 1], wave, lane);
            stage_tile(Vh + (blk + 1) * 64, SEQ, sV[cur ^ 1], wave, lane);
        }
        if (blk <= tA)
            compute(sK[cur], sV[cur], qfA0, qfA1, oA, lsA, blk == tA);
        compute(sK[cur], sV[cur], qfB0, qfB1, oB, lsB, blk == tB);
        __syncthreads();
        cur ^= 1;
    }

    auto finish = [&](f32x4* o, float ls, int q0) {
        float tot = ls;
        tot += __shfl_xor(tot, 16, 64);
        tot += __shfl_xor(tot, 32, 64);
        float inv[4];
        #pragma unroll
        for (int r = 0; r < 4; ++r)
            inv[r] = 1.0f / __shfl(tot, lg * 4 + r, 64);
        #pragma unroll
        for (int n = 0; n < 4; ++n)
            #pragma unroll
            for (int r = 0; r < 4; ++r) {
                const int i = q0 + lg * 4 + r;
                X[((size_t)i * BATCH + b) * DM + h * DK + 16 * n + l15] =
                    f2bf(o[n][r] * inv[r]);
            }
    };
    finish(oA, lsA, qA);
    finish(oB, lsB, qB);
}

extern "C" void kernel_launch(void* const* d_in, const int* in_sizes, int n_in,
                              void* d_out, int out_size, void* d_ws, size_t ws_size,
                              hipStream_t stream) {
    const float* query = (const float*)d_in[0];
    const float* key   = (const float*)d_in[1];
    const float* value = (const float*)d_in[2];
    const float* Wq = (const float*)d_in[4];
    const float* bq = (const float*)d_in[5];
    const float* Wk = (const float*)d_in[6];
    const float* bk = (const float*)d_in[7];
    const float* Wv = (const float*)d_in[8];
    const float* bv = (const float*)d_in[9];
    const float* Wo = (const float*)d_in[10];
    const float* bo = (const float*)d_in[11];

    const size_t NELEM = (size_t)SEQ * BATCH * DM;
    const size_t WM    = (size_t)DM * DM;
    u16* Qb  = (u16*)d_ws;
    u16* Kb  = Qb + NELEM;
    u16* Vt  = Kb + NELEM;
    u16* Xb  = Vt + NELEM;
    u16* Wbf = Xb + NELEM;        // Wq|Wk|Wv|Wo bf16

    dim3 gb(256);
    hipLaunchKernelGGL(conv_w, dim3(2048), gb, 0, stream, Wq, Wk, Wv, Wo, Wbf);
    hipLaunchKernelGGL(gemm_qkv, dim3(64, 24), gb, 0, stream,
                       query, key, value, Wbf, bq, bk, bv, Qb, Kb, Vt);
    hipLaunchKernelGGL(attn_fwd, dim3(16, NBH), gb, 0, stream, Qb, Kb, Vt, Xb);
    hipLaunchKernelGGL(gemm_bf, dim3(64, 8), gb, 0, stream,
                       Xb, Wbf + 3 * WM, bo, (float*)d_out);
}

// Round 21
// 162.871 us; speedup vs baseline: 1.9692x; 1.9692x over previous
//
#include <hip/hip_runtime.h>
#include <hip/hip_bf16.h>

#define SEQ 2048
#define BATCH 4
#define DM 1024
#define HEADS 16
#define DK 64
#define NBH 64
#define SC_LOG2E (0.125f * 1.4426950408889634f)

typedef unsigned short u16;
typedef __attribute__((ext_vector_type(8))) short bf16x8;
typedef __attribute__((ext_vector_type(4))) float f32x4;

__device__ inline u16 f2bf(float f) {
    unsigned int u = __builtin_bit_cast(unsigned int, f);
    u += 0x7fffu + ((u >> 16) & 1u);   // RNE
    return (u16)(u >> 16);
}
__device__ inline float fexp2(float x) {
    float r; asm("v_exp_f32 %0, %1" : "=v"(r) : "v"(x)); return r;
}
__device__ inline unsigned pkbf(float a, float b) {   // lo=a, hi=b (RNE)
    unsigned r; asm("v_cvt_pk_bf16_f32 %0, %1, %2" : "=v"(r) : "v"(a), "v"(b)); return r;
}

// ---------------- weights-only fp32 -> bf16 conversion (24 MB ~ 5 us) -------
__global__ __launch_bounds__(256)
void conv_w(const float* __restrict__ wq, const float* __restrict__ wk,
            const float* __restrict__ wv, const float* __restrict__ wo,
            u16* __restrict__ ow)
{
    const size_t W8 = (size_t)DM * DM / 8;             // 131,072
    size_t i = (size_t)blockIdx.x * 256 + threadIdx.x; // grid 2048 = 4*W8/256
    int wsel = (int)(i >> 17);
    size_t off = i & (W8 - 1);
    const float* src = wsel == 0 ? wq : wsel == 1 ? wk : wsel == 2 ? wv : wo;
    u16* dst = ow + (size_t)wsel * DM * DM;
    float4 a = ((const float4*)src)[off * 2];
    float4 b = ((const float4*)src)[off * 2 + 1];
    uint4 w;
    w.x = pkbf(a.x, a.y); w.y = pkbf(a.z, a.w);
    w.z = pkbf(b.x, b.y); w.w = pkbf(b.z, b.w);
    *(uint4*)(dst + off * 8) = w;
}

// ---------------- shared GEMM pieces ------------------
__device__ inline void gstage(const u16* __restrict__ src, u16* dst,
                              int wave, int lane) {
    #pragma unroll
    for (int i = 0; i < 4; ++i) {
        int ci = (i * 4 + wave) * 64 + lane;
        int row = ci >> 3, ch = ci & 7;
        const u16* g = src + (size_t)row * 1024 + ((ch ^ (row & 7)) << 3);
        u16* l = dst + (i * 4 + wave) * 512;
        __builtin_amdgcn_global_load_lds(
            (const __attribute__((address_space(1))) unsigned int*)g,
            (__attribute__((address_space(3))) unsigned int*)l, 16, 0, 0);
    }
}
__device__ inline bf16x8 rdt(const u16* t, int row, int ch) {
    return *(const bf16x8*)(t + row * 64 + ((ch ^ (row & 7)) << 3));
}

// ---------------- bf16-A GEMM (output projection, fp32 out; r16 exact) ------
__global__ __launch_bounds__(256, 2)
void gemm_bf(const u16* __restrict__ A, const u16* __restrict__ B,
             const float* __restrict__ bias, float* __restrict__ Out)
{
    __shared__ __align__(16) u16 sA[2][128 * 64];
    __shared__ __align__(16) u16 sB[2][128 * 64];
    const int tid  = threadIdx.x;
    const int lane = tid & 63, wave = tid >> 6;
    const int wr = (wave >> 1) * 64, wc = (wave & 1) * 64;
    const int l15 = lane & 15, lg = lane >> 4;
    const int row0 = blockIdx.x * 128, col0 = blockIdx.y * 128;
    const u16* Abase = A + (size_t)row0 * 1024;
    const u16* Bbase = B + (size_t)col0 * 1024;

    f32x4 acc[4][4];
    #pragma unroll
    for (int m = 0; m < 4; ++m)
        #pragma unroll
        for (int n = 0; n < 4; ++n) acc[m][n] = (f32x4){0.f, 0.f, 0.f, 0.f};

    gstage(Abase, sA[0], wave, lane);
    gstage(Bbase, sB[0], wave, lane);
    __syncthreads();

    int cur = 0;
    for (int kt = 0; kt < 16; ++kt) {
        if (kt < 15) {
            gstage(Abase + (kt + 1) * 64, sA[cur ^ 1], wave, lane);
            gstage(Bbase + (kt + 1) * 64, sB[cur ^ 1], wave, lane);
        }
        #pragma unroll
        for (int s = 0; s < 2; ++s) {
            bf16x8 af[4], bf[4];
            #pragma unroll
            for (int m = 0; m < 4; ++m)
                af[m] = rdt(sA[cur], wr + m * 16 + l15, s * 4 + lg);
            #pragma unroll
            for (int n = 0; n < 4; ++n)
                bf[n] = rdt(sB[cur], wc + n * 16 + l15, s * 4 + lg);
            __builtin_amdgcn_s_setprio(1);
            #pragma unroll
            for (int m = 0; m < 4; ++m)
                #pragma unroll
                for (int n = 0; n < 4; ++n)
                    acc[m][n] = __builtin_amdgcn_mfma_f32_16x16x32_bf16(
                        af[m], bf[n], acc[m][n], 0, 0, 0);
            __builtin_amdgcn_s_setprio(0);
        }
        __syncthreads();
        cur ^= 1;
    }
    #pragma unroll
    for (int m = 0; m < 4; ++m)
        #pragma unroll
        for (int n = 0; n < 4; ++n)
            #pragma unroll
            for (int r = 0; r < 4; ++r) {
                int R = row0 + wr + m * 16 + lg * 4 + r;
                int E = col0 + wc + n * 16 + l15;
                Out[(size_t)R * 1024 + E] = acc[m][n][r] + bias[E];
            }
}

// ---------------- merged Q/K/V projection GEMM (round-16 exact) -------------
// sA single-buffered (VALU-written, split barrier): LDS 48 KB -> 3 blocks/CU.
__global__ __launch_bounds__(256, 3)
void gemm_qkv(const float* __restrict__ q, const float* __restrict__ k,
              const float* __restrict__ v, const u16* __restrict__ Wbf,
              const float* __restrict__ bq, const float* __restrict__ bk,
              const float* __restrict__ bv,
              u16* __restrict__ Qb, u16* __restrict__ Kb, u16* __restrict__ Vt)
{
    __shared__ __align__(16) u16 sA[128 * 64];       // single buffer
    __shared__ __align__(16) u16 sB[2][128 * 64];
    const int g = blockIdx.y >> 3;                 // 0=Q, 1=K, 2=V
    const float* A    = g == 0 ? q  : g == 1 ? k  : v;
    const float* bias = g == 0 ? bq : g == 1 ? bk : bv;
    u16* Out          = g == 0 ? Qb : g == 1 ? Kb : Vt;
    const u16* B = Wbf + (size_t)g * DM * DM;
    const float oscale = g == 0 ? SC_LOG2E : 1.0f;
    const bool vmode = (g == 2);

    const int tid  = threadIdx.x;
    const int lane = tid & 63, wave = tid >> 6;
    const int wr = (wave >> 1) * 64, wc = (wave & 1) * 64;
    const int l15 = lane & 15, lg = lane >> 4;
    const int row0 = blockIdx.x * 128, col0 = (blockIdx.y & 7) * 128;
    const int arow = tid >> 4;          // 16 lanes per A row
    const int ach  = tid & 15;          // 16B chunk within the row's 256B slab
    const float* Ag = A + (size_t)(row0 + arow) * 1024 + ach * 4;
    const u16* Bbase = B + (size_t)col0 * 1024;

    f32x4 acc[4][4];
    #pragma unroll
    for (int m = 0; m < 4; ++m)
        #pragma unroll
        for (int n = 0; n < 4; ++n) acc[m][n] = (f32x4){0.f, 0.f, 0.f, 0.f};

    auto loadA = [&](int kt, float4* r) {
        #pragma unroll
        for (int i = 0; i < 8; ++i)     // pass i: rows arow + 16*i
            r[i] = *(const float4*)(Ag + (size_t)i * 16 * 1024 + kt * 64);
    };
    auto writeA = [&](const float4* r) {
        const int c16 = ach >> 1, half = ach & 1;
        #pragma unroll
        for (int i = 0; i < 8; ++i) {
            int row = arow + 16 * i;
            uint2 w;
            w.x = pkbf(r[i].x, r[i].y);
            w.y = pkbf(r[i].z, r[i].w);
            *(uint2*)(sA + row * 64 + ((c16 ^ (row & 7)) << 3) + half * 4) = w;
        }
    };

    {
        float4 a0[8];
        loadA(0, a0);
        gstage(Bbase, sB[0], wave, lane);
        writeA(a0);
    }
    __syncthreads();

    int cur = 0;
    for (int kt = 0; kt < 16; ++kt) {
        float4 an[8];
        const bool pre = (kt < 15);
        if (pre) {
            loadA(kt + 1, an);                          // issue early (T14)
            gstage(Bbase + (kt + 1) * 64, sB[cur ^ 1], wave, lane);
        }
        #pragma unroll
        for (int s = 0; s < 2; ++s) {
            bf16x8 af[4], bf[4];
            #pragma unroll
            for (int m = 0; m < 4; ++m)
                af[m] = rdt(sA, wr + m * 16 + l15, s * 4 + lg);
            #pragma unroll
            for (int n = 0; n < 4; ++n)
                bf[n] = rdt(sB[cur], wc + n * 16 + l15, s * 4 + lg);
            __builtin_amdgcn_s_setprio(1);
            #pragma unroll
            for (int m = 0; m < 4; ++m)
                #pragma unroll
                for (int n = 0; n < 4; ++n)
                    acc[m][n] = __builtin_amdgcn_mfma_f32_16x16x32_bf16(
                        af[m], bf[n], acc[m][n], 0, 0, 0);
            __builtin_amdgcn_s_setprio(0);
        }
        __syncthreads();          // all sA reads done; vmcnt (an + B gload) drains
        if (pre) writeA(an);      // overwrite single sA
        __syncthreads();          // ds_writes visible before next iter's reads
        cur ^= 1;
    }

    #pragma unroll
    for (int m = 0; m < 4; ++m)
        #pragma unroll
        for (int n = 0; n < 4; ++n)
            #pragma unroll
            for (int r = 0; r < 4; ++r) {
                int R = row0 + wr + m * 16 + lg * 4 + r;
                int E = col0 + wc + n * 16 + l15;
                float val = (acc[m][n][r] + bias[E]) * oscale;
                int s = R >> 2, b = R & 3, hh = E >> 6, d = E & 63;
                size_t idx = vmode
                    ? ((size_t)(b * HEADS + hh) * DK + d) * SEQ + s
                    : ((size_t)(b * HEADS + hh) * SEQ + s) * DK + d;
                Out[idx] = f2bf(val);
            }
}

// ---------------- causal flash attention (round-10 exact) -------------------
__device__ inline void stage_tile(const u16* __restrict__ srcRow0, int srcStride,
                                  u16* tile, int wave, int lane) {
    #pragma unroll
    for (int i = 0; i < 2; ++i) {
        int row = wave * 16 + i * 8 + (lane >> 3);
        int chunk = (lane & 7) ^ (row & 7);
        const u16* g = srcRow0 + (size_t)row * srcStride + chunk * 8;
        u16* l = tile + (wave * 16 + i * 8) * 64;
        __builtin_amdgcn_global_load_lds(
            (const __attribute__((address_space(1))) unsigned int*)g,
            (__attribute__((address_space(3))) unsigned int*)l, 16, 0, 0);
    }
}
__device__ inline bf16x8 tread(const u16* tile, int row, int chunk) {
    return *(const bf16x8*)((const char*)tile + row * 128 + ((chunk ^ (row & 7)) << 4));
}

__global__ __launch_bounds__(256, 4)
void attn_fwd(const u16* __restrict__ Q, const u16* __restrict__ K,
              const u16* __restrict__ V, u16* __restrict__ X)
{
    __shared__ __align__(16) u16 sK[2][4096];
    __shared__ __align__(16) u16 sV[2][4096];
    __shared__ __align__(16) u16 plds[4][16 * 64];

    const int lin = blockIdx.x + 16 * blockIdx.y;
    const int xcd = lin & 7, ii = lin >> 3;
    const int bh  = (ii & 7) | (xcd << 3);   // 8 bh per XCD (KV fits L2)
    const int tA  = ii >> 3;                  // 0..15
    const int tB  = 31 - tA;                  // 16..31
    const int b = bh >> 4, h = bh & 15;
    const int lane = threadIdx.x & 63, wave = threadIdx.x >> 6;
    const int l15 = lane & 15, lg = lane >> 4;
    const int qloc = wave * 16 + l15;
    const int swz = (l15 & 7) << 4;
    const u16* Qh = Q + (size_t)bh * SEQ * DK;
    const u16* Kh = K + (size_t)bh * SEQ * DK;
    const u16* Vh = V + (size_t)bh * SEQ * DK;   // [DK][SEQ]

    const int qA = tA * 64 + wave * 16, qB = tB * 64 + wave * 16;
    const bf16x8 qfA0 = *(const bf16x8*)&Qh[(size_t)(qA + l15) * DK + lg * 8];
    const bf16x8 qfA1 = *(const bf16x8*)&Qh[(size_t)(qA + l15) * DK + 32 + lg * 8];
    const bf16x8 qfB0 = *(const bf16x8*)&Qh[(size_t)(qB + l15) * DK + lg * 8];
    const bf16x8 qfB1 = *(const bf16x8*)&Qh[(size_t)(qB + l15) * DK + 32 + lg * 8];

    f32x4 oA[4], oB[4];
    #pragma unroll
    for (int n = 0; n < 4; ++n) {
        oA[n] = (f32x4){0.f, 0.f, 0.f, 0.f};
        oB[n] = (f32x4){0.f, 0.f, 0.f, 0.f};
    }
    float lsA = 0.f, lsB = 0.f;
    u16* pw = &plds[wave][0];

    auto compute = [&](const u16* kt, const u16* vt,
                       const bf16x8& q0v, const bf16x8& q1v,
                       f32x4* o, float& ls, bool diag) {
        f32x4 sc[4];
        #pragma unroll
        for (int c = 0; c < 4; ++c) sc[c] = (f32x4){0.f, 0.f, 0.f, 0.f};

        __builtin_amdgcn_s_setprio(1);
        #pragma unroll
        for (int c = 0; c < 4; ++c) {
            bf16x8 k0 = tread(kt, 16 * c + l15, lg);
            bf16x8 k1 = tread(kt, 16 * c + l15, 4 + lg);
            sc[c] = __builtin_amdgcn_mfma_f32_16x16x32_bf16(k0, q0v, sc[c], 0, 0, 0);
            sc[c] = __builtin_amdgcn_mfma_f32_16x16x32_bf16(k1, q1v, sc[c], 0, 0, 0);
        }
        __builtin_amdgcn_s_setprio(0);

        #pragma unroll
        for (int c = 0; c < 4; ++c) {
            float p[4];
            #pragma unroll
            for (int r = 0; r < 4; ++r) {
                float e = fexp2(sc[c][r]);
                if (diag) {
                    int kl = 16 * c + 4 * lg + r;
                    e = (kl <= qloc) ? e : 0.f;
                }
                p[r] = e;
                ls += e;
            }
            uint2 w;
            w.x = pkbf(p[0], p[1]);
            w.y = pkbf(p[2], p[3]);
            *(uint2*)((char*)pw + l15 * 128 + ((32 * c + 8 * lg) ^ swz)) = w;
        }
        asm volatile("s_waitcnt lgkmcnt(0)" ::: "memory");
        __builtin_amdgcn_sched_barrier(0);
        bf16x8 pf0 = *(const bf16x8*)((const char*)pw + l15 * 128 + ((16 * lg) ^ swz));
        bf16x8 pf1 = *(const bf16x8*)((const char*)pw + l15 * 128 + ((64 + 16 * lg) ^ swz));

        __builtin_amdgcn_s_setprio(1);
        #pragma unroll
        for (int n = 0; n < 4; ++n) {
            bf16x8 v0 = tread(vt, 16 * n + l15, lg);
            bf16x8 v1 = tread(vt, 16 * n + l15, 4 + lg);
            o[n] = __builtin_amdgcn_mfma_f32_16x16x32_bf16(pf0, v0, o[n], 0, 0, 0);
            o[n] = __builtin_amdgcn_mfma_f32_16x16x32_bf16(pf1, v1, o[n], 0, 0, 0);
        }
        __builtin_amdgcn_s_setprio(0);
    };

    stage_tile(Kh, DK, sK[0], wave, lane);
    stage_tile(Vh, SEQ, sV[0], wave, lane);
    __syncthreads();

    const int nst = tB + 1;
    int cur = 0;
    for (int blk = 0; blk < nst; ++blk) {
        if (blk + 1 < nst) {
            stage_tile(Kh + (size_t)(blk + 1) * 64 * DK, DK, sK[cur ^ 1], wave, lane);
            stage_tile(Vh + (blk + 1) * 64, SEQ, sV[cur ^ 1], wave, lane);
        }
        if (blk <= tA)
            compute(sK[cur], sV[cur], qfA0, qfA1, oA, lsA, blk == tA);
        compute(sK[cur], sV[cur], qfB0, qfB1, oB, lsB, blk == tB);
        __syncthreads();
        cur ^= 1;
    }

    auto finish = [&](f32x4* o, float ls, int q0) {
        float tot = ls;
        tot += __shfl_xor(tot, 16, 64);
        tot += __shfl_xor(tot, 32, 64);
        float inv[4];
        #pragma unroll
        for (int r = 0; r < 4; ++r)
            inv[r] = 1.0f / __shfl(tot, lg * 4 + r, 64);
        #pragma unroll
        for (int n = 0; n < 4; ++n)
            #pragma unroll
            for (int r = 0; r < 4; ++r) {
                const int i = q0 + lg * 4 + r;
                X[((size_t)i * BATCH + b) * DM + h * DK + 16 * n + l15] =
                    f2bf(o[n][r] * inv[r]);
            }
    };
    finish(oA, lsA, qA);
    finish(oB, lsB, qB);
}

extern "C" void kernel_launch(void* const* d_in, const int* in_sizes, int n_in,
                              void* d_out, int out_size, void* d_ws, size_t ws_size,
                              hipStream_t stream) {
    const float* query = (const float*)d_in[0];
    const float* key   = (const float*)d_in[1];
    const float* value = (const float*)d_in[2];
    const float* Wq = (const float*)d_in[4];
    const float* bq = (const float*)d_in[5];
    const float* Wk = (const float*)d_in[6];
    const float* bk = (const float*)d_in[7];
    const float* Wv = (const float*)d_in[8];
    const float* bv = (const float*)d_in[9];
    const float* Wo = (const float*)d_in[10];
    const float* bo = (const float*)d_in[11];

    const size_t NELEM = (size_t)SEQ * BATCH * DM;
    const size_t WM    = (size_t)DM * DM;
    u16* Qb  = (u16*)d_ws;
    u16* Kb  = Qb + NELEM;
    u16* Vt  = Kb + NELEM;
    u16* Xb  = Vt + NELEM;
    u16* Wbf = Xb + NELEM;        // Wq|Wk|Wv|Wo bf16

    dim3 gb(256);
    hipLaunchKernelGGL(conv_w, dim3(2048), gb, 0, stream, Wq, Wk, Wv, Wo, Wbf);
    hipLaunchKernelGGL(gemm_qkv, dim3(64, 24), gb, 0, stream,
                       query, key, value, Wbf, bq, bk, bv, Qb, Kb, Vt);
    hipLaunchKernelGGL(attn_fwd, dim3(16, NBH), gb, 0, stream, Qb, Kb, Vt, Xb);
    hipLaunchKernelGGL(gemm_bf, dim3(64, 8), gb, 0, stream,
                       Xb, Wbf + 3 * WM, bo, (float*)d_out);
}